// Round 3
// baseline (602.887 us; speedup 1.0000x reference)
//
#include <hip/hip_runtime.h>
#include <stdint.h>

// Qwen2 attention layer: B=1, S=2048, H=4096, NH=32, NKV=4, HD=128, causal GQA + RoPE.
// Pipeline: cvt(fp32->bf16) -> QKV gemm_bt (bf16 MFMA) -> RoPE(+q scale) -> V transpose
//           -> flash attention (KV-split, <=16 tiles/WG, fp32 partials) -> reduce -> O gemm_bt.

using bf16x8 = __attribute__((ext_vector_type(8))) short;          // MFMA A/B frag (8 bf16, 4 VGPR)
using f32x4  = __attribute__((ext_vector_type(4))) float;          // MFMA C/D frag
using u16    = unsigned short;
using u16x4  = __attribute__((ext_vector_type(4))) unsigned short; // 8B store
using u16x8  = __attribute__((ext_vector_type(8))) unsigned short; // 16B copy type

#define S_TOK   2048
#define HID     4096
#define QKV_N   5120   // 4096 q + 512 k + 512 v
#define K_OFF   4096
#define V_OFF   4608
#define NHEAD   32
#define NKVH    4

__device__ __forceinline__ float bf2f(u16 u) {
  unsigned v = ((unsigned)u) << 16;
  return __builtin_bit_cast(float, v);
}
__device__ __forceinline__ u16 f2bf(float f) {   // round-to-nearest-even
  unsigned u = __builtin_bit_cast(unsigned, f);
  u += 0x7fffu + ((u >> 16) & 1u);
  return (u16)(u >> 16);
}

// ---------------- fp32 -> bf16 convert (vectorized, grid-stride) ----------------
__global__ void cvt_kernel(const float* __restrict__ src, u16* __restrict__ dst, int n4) {
  int stride = gridDim.x * blockDim.x;
  for (int i = blockIdx.x * blockDim.x + threadIdx.x; i < n4; i += stride) {
    f32x4 v = ((const f32x4*)src)[i];
    union { u16 a[4]; unsigned long long ll; } o;
    o.a[0] = f2bf(v[0]); o.a[1] = f2bf(v[1]); o.a[2] = f2bf(v[2]); o.a[3] = f2bf(v[3]);
    ((unsigned long long*)dst)[i] = o.ll;
  }
}

// ---------------- bias concat (q_b | k_b | v_b) -> fp32[5120] ----------------
__global__ void biascat_kernel(const float* __restrict__ qb, const float* __restrict__ kb,
                               const float* __restrict__ vb, float* __restrict__ out) {
  int i = blockIdx.x * 256 + threadIdx.x;
  if (i >= QKV_N) return;
  float v;
  if (i < K_OFF) v = qb[i];
  else if (i < V_OFF) v = kb[i - K_OFF];
  else v = vb[i - V_OFF];
  out[i] = v;
}

// ---------------- async global->LDS (16B per lane, dest = wave base + lane*16) ----------------
__device__ __forceinline__ void gload_lds16(const void* g, void* l) {
  __builtin_amdgcn_global_load_lds(
      (const __attribute__((address_space(1))) void*)g,
      (__attribute__((address_space(3))) void*)l, 16, 0, 0);
}

// ---------------- GEMM: C[M,N] = A[M,K] @ B[N,K]^T (+bias), bf16 in, fp32 acc ----------------
// m97 structure: 128x128 tile, BK=64, 4 waves (2x2 of 64x64), 16x16x32 bf16 MFMA,
// global_load_lds width 16, single-buffered LDS, 2 barriers per K-step.
// + bijective XCD swizzle (T1).
template <int BF16OUT, int BIAS>
__global__ __launch_bounds__(256, 2)
void gemm_bt_kernel(const u16* __restrict__ A, const u16* __restrict__ Bm,
                    void* __restrict__ C, const float* __restrict__ bias,
                    int M, int N, int K) {
  __shared__ __align__(16) u16 lA[128 * 64];
  __shared__ __align__(16) u16 lB[128 * 64];
  const int tid  = threadIdx.x;
  const int wave = tid >> 6, lane = tid & 63;
  const int lg = lane >> 4, l15 = lane & 15;

  // XCD swizzle (grids here have nwg % 8 == 0)
  const int nwg  = gridDim.x * gridDim.y;
  const int orig = blockIdx.y * gridDim.x + blockIdx.x;
  const int cpx  = nwg >> 3;
  const int swz  = (orig & 7) * cpx + (orig >> 3);
  const int bx   = swz % gridDim.x, by = swz / gridDim.x;

  const int m0 = by * 128, n0 = bx * 128;
  const int wr = wave >> 1, wc = wave & 1;

  f32x4 acc[4][4] = {};

  for (int k0 = 0; k0 < K; k0 += 64) {
#pragma unroll
    for (int i = 0; i < 4; ++i) {
      int c = wave * 4 + i;          // chunk 0..15, 1KB each (64 lanes x 16B)
      int s = c * 64 + lane;         // slot -> row/col of [128][64] tile
      int row = s >> 3;
      int col = (s & 7) << 3;
      gload_lds16(A  + (size_t)(m0 + row) * K + k0 + col, &lA[c * 512]);
      gload_lds16(Bm + (size_t)(n0 + row) * K + k0 + col, &lB[c * 512]);
    }
    __syncthreads();
#pragma unroll
    for (int kk = 0; kk < 2; ++kk) {
      bf16x8 af[4], bfr[4];
#pragma unroll
      for (int mi = 0; mi < 4; ++mi)
        af[mi] = *(const bf16x8*)&lA[(wr * 64 + mi * 16 + l15) * 64 + kk * 32 + lg * 8];
#pragma unroll
      for (int ni = 0; ni < 4; ++ni)
        bfr[ni] = *(const bf16x8*)&lB[(wc * 64 + ni * 16 + l15) * 64 + kk * 32 + lg * 8];
#pragma unroll
      for (int mi = 0; mi < 4; ++mi)
#pragma unroll
        for (int ni = 0; ni < 4; ++ni)
          acc[mi][ni] = __builtin_amdgcn_mfma_f32_16x16x32_bf16(af[mi], bfr[ni], acc[mi][ni], 0, 0, 0);
    }
    __syncthreads();
  }

  // epilogue: D layout col=lane&15, row=(lane>>4)*4+reg  [m89-verified]
#pragma unroll
  for (int mi = 0; mi < 4; ++mi) {
#pragma unroll
    for (int ni = 0; ni < 4; ++ni) {
      int r0 = m0 + wr * 64 + mi * 16 + lg * 4;
      int cc = n0 + wc * 64 + ni * 16 + l15;
      float bv = BIAS ? bias[cc] : 0.0f;
#pragma unroll
      for (int r = 0; r < 4; ++r) {
        float v = acc[mi][ni][r] + bv;
        if (BF16OUT) ((u16*)C)[(size_t)(r0 + r) * N + cc] = f2bf(v);
        else         ((float*)C)[(size_t)(r0 + r) * N + cc] = v;
      }
    }
  }
}

// ---------------- RoPE in-place on q,k regions of qkv; folds 1/sqrt(HD) into q ----------------
__global__ void rope_kernel(u16* __restrict__ qkv, const int* __restrict__ pos_ids) {
  const int tid  = threadIdx.x;
  const int gid  = blockIdx.x * 4 + (tid >> 6);   // (s, head) pair; 2048*36 total
  const int lane = tid & 63;                       // d in [0,64)
  const int s = gid / 36, hh = gid - s * 36;       // hh: 0..31 q heads, 32..35 k heads
  const float pos = (float)pos_ids[s];
  const float inv = exp2f((float)lane * -0.20762050593f);  // 10000^(-d/64)
  float sn, cs;
  sincosf(pos * inv, &sn, &cs);
  size_t base = (size_t)s * QKV_N + (hh < 32 ? hh * 128 : K_OFF + (hh - 32) * 128);
  float x1 = bf2f(qkv[base + lane]);
  float x2 = bf2f(qkv[base + lane + 64]);
  float o1 = x1 * cs - x2 * sn;
  float o2 = x2 * cs + x1 * sn;
  if (hh < 32) { o1 *= 0.08838834764831845f; o2 *= 0.08838834764831845f; }
  qkv[base + lane]      = f2bf(o1);
  qkv[base + lane + 64] = f2bf(o2);
}

// ---------------- V transpose: qkv v-cols [2048][512] -> vt [512][2048] ----------------
__global__ void vtrans_kernel(const u16* __restrict__ qkv, u16* __restrict__ vt) {
  __shared__ u16 t[32][33];
  const int tx = threadIdx.x & 31, ty = threadIdx.x >> 5;  // 32x8
  const int bc = blockIdx.x;  // 16 col tiles (512/32)
  const int bs = blockIdx.y;  // 64 row tiles (2048/32)
#pragma unroll
  for (int i = 0; i < 4; ++i)
    t[ty + i * 8][tx] = qkv[(size_t)(bs * 32 + ty + i * 8) * QKV_N + V_OFF + bc * 32 + tx];
  __syncthreads();
#pragma unroll
  for (int i = 0; i < 4; ++i)
    vt[(size_t)(bc * 32 + ty + i * 8) * S_TOK + bs * 32 + tx] = t[tx][ty + i * 8];
}

// ---------------- Flash attention with KV split (flash-decoding) ----------------
// Grid: 1536 = 32 heads x 48 chunks. Per head h, chunk r:
//   r in [0,16):  qt = 16+r, part c=0, tiles [0,16)   (no diag)  -> partial slot
//   r in [16,32): qt = 47-r, part c=1, tiles [16,qt]  (diag)     -> partial slot
//   r in [32,48): qt = 47-r (<16),     tiles [0,qt]   (diag)     -> direct aout
// Every WG runs <=16 KV tiles -> balanced; 1536 WGs, 40KB LDS -> 4 WGs/CU.
// Staging: T14 reg-prefetch of tile t+1 (global->reg early, ds_write after barrier).
__global__ __launch_bounds__(256, 4)
void attn_kernel(const u16* __restrict__ qkv, const u16* __restrict__ vt,
                 u16* __restrict__ aout, float* __restrict__ Opart,
                 float* __restrict__ Mpart, float* __restrict__ Lpart) {
  __shared__ __align__(16) u16 Kl[64 * 128];      // K tile, rows 256B, XOR-swizzled
  __shared__ __align__(16) u16 Vl[128 * 64];      // V^T tile, rows 128B, XOR-swizzled
  __shared__ __align__(16) u16 Pl[4 * 16 * 64];   // per-wave P, XOR-swizzled rows (128B)
  const int tid = threadIdx.x, wave = tid >> 6, lane = tid & 63;
  const int lg = lane >> 4, l15 = lane & 15;

  const int bid = blockIdx.x;
  const int h = bid / 48;
  const int r = bid - h * 48;
  int qt, t0, t1, cpart;
  bool diag;
  if (r < 16)      { qt = 16 + r; t0 = 0;  t1 = 15; cpart = 0; diag = false; }
  else if (r < 32) { qt = 47 - r; t0 = 16; t1 = qt; cpart = 1; diag = true;  }
  else             { qt = 47 - r; t0 = 0;  t1 = qt; cpart = 0; diag = true;  }
  const int kvh = h >> 3;
  const int q0 = qt * 64;

  // Q fragments hoisted to registers
  bf16x8 qf[4];
  {
    const u16* qp = qkv + (size_t)(q0 + wave * 16 + l15) * QKV_N + h * 128 + lg * 8;
#pragma unroll
    for (int kk = 0; kk < 4; ++kk) qf[kk] = *(const bf16x8*)(qp + kk * 32);
  }

  // Per-lane staging geometry (4 chunks of 1KB each per thread-quarter).
  int krow[4], kcol, vrow[4], vcol;
  kcol = (lane & 15) * 8;
  vcol = (lane & 7) * 8;
#pragma unroll
  for (int i = 0; i < 4; ++i) {
    int c = wave * 4 + i;
    krow[i] = c * 4 + (lane >> 4);   // 0..63
    vrow[i] = c * 8 + (lane >> 3);   // 0..127 (d index)
  }
  const u16* kbase = qkv + K_OFF + kvh * 128;
  const u16* vbase = vt + (size_t)kvh * 128 * S_TOK;

  f32x4 o[8];
#pragma unroll
  for (int i = 0; i < 8; ++i) o[i] = f32x4{0.f, 0.f, 0.f, 0.f};
  float mrow[4] = {-3e38f, -3e38f, -3e38f, -3e38f};
  float lrow[4] = {0.f, 0.f, 0.f, 0.f};

  // prologue: stage tile t0
  u16x8 kr[4], vr[4];
#pragma unroll
  for (int i = 0; i < 4; ++i) {
    kr[i] = *(const u16x8*)(kbase + (size_t)(t0 * 64 + krow[i]) * QKV_N + kcol);
    vr[i] = *(const u16x8*)(vbase + (size_t)vrow[i] * S_TOK + t0 * 64 + vcol);
  }
#pragma unroll
  for (int i = 0; i < 4; ++i) {
    *(u16x8*)((char*)Kl + krow[i] * 256 + ((kcol * 2) ^ ((krow[i] & 7) << 4))) = kr[i];
    *(u16x8*)((char*)Vl + vrow[i] * 128 + ((vcol * 2) ^ ((vrow[i] & 7) << 4))) = vr[i];
  }
  __syncthreads();

  for (int t = t0; t <= t1; ++t) {
    // issue next-tile global loads early; HBM/L2 latency hides under this step's compute
    if (t < t1) {
#pragma unroll
      for (int i = 0; i < 4; ++i) {
        kr[i] = *(const u16x8*)(kbase + (size_t)((t + 1) * 64 + krow[i]) * QKV_N + kcol);
        vr[i] = *(const u16x8*)(vbase + (size_t)vrow[i] * S_TOK + (t + 1) * 64 + vcol);
      }
    }
    const int kv0 = t * 64;
    const bool dg = diag && (t == t1);

    // S = Q K^T
    f32x4 sc[4];
#pragma unroll
    for (int jb = 0; jb < 4; ++jb) {
      f32x4 a = {0.f, 0.f, 0.f, 0.f};
      int j = jb * 16 + l15;
      const char* kb = (const char*)Kl + j * 256;
      int swzk = (j & 7) << 4;
#pragma unroll
      for (int kk = 0; kk < 4; ++kk) {
        bf16x8 bfr = *(const bf16x8*)(kb + (((kk * 32 + lg * 8) * 2) ^ swzk));
        a = __builtin_amdgcn_mfma_f32_16x16x32_bf16(qf[kk], bfr, a, 0, 0, 0);
      }
      sc[jb] = a;
    }

    // causal mask (diag tile only) + online softmax; rows r_local = lg*4+rr
    float tmax[4] = {-3e38f, -3e38f, -3e38f, -3e38f};
#pragma unroll
    for (int jb = 0; jb < 4; ++jb) {
      int jg = kv0 + jb * 16 + l15;
#pragma unroll
      for (int rr = 0; rr < 4; ++rr) {
        float v = sc[jb][rr];
        if (dg && (jg > q0 + wave * 16 + lg * 4 + rr)) v = -3e38f;
        sc[jb][rr] = v;
        tmax[rr] = fmaxf(tmax[rr], v);
      }
    }
#pragma unroll
    for (int off = 1; off < 16; off <<= 1)
#pragma unroll
      for (int rr = 0; rr < 4; ++rr) tmax[rr] = fmaxf(tmax[rr], __shfl_xor(tmax[rr], off, 64));
    float alpha[4], psum[4];
#pragma unroll
    for (int rr = 0; rr < 4; ++rr) {
      float mn = fmaxf(mrow[rr], tmax[rr]);
      alpha[rr] = __expf(mrow[rr] - mn);
      mrow[rr] = mn;
      psum[rr] = 0.f;
    }
#pragma unroll
    for (int jb = 0; jb < 4; ++jb)
#pragma unroll
      for (int rr = 0; rr < 4; ++rr) {
        float p = __expf(sc[jb][rr] - mrow[rr]);
        sc[jb][rr] = p;
        psum[rr] += p;
      }
#pragma unroll
    for (int off = 1; off < 16; off <<= 1)
#pragma unroll
      for (int rr = 0; rr < 4; ++rr) psum[rr] += __shfl_xor(psum[rr], off, 64);
#pragma unroll
    for (int rr = 0; rr < 4; ++rr) lrow[rr] = lrow[rr] * alpha[rr] + psum[rr];
#pragma unroll
    for (int db = 0; db < 8; ++db)
#pragma unroll
      for (int rr = 0; rr < 4; ++rr) o[db][rr] *= alpha[rr];

    // write P (bf16) to per-wave LDS region (wave-private; no cross-wave barrier needed)
    {
      char* pw = (char*)(Pl + wave * 1024);
#pragma unroll
      for (int jb = 0; jb < 4; ++jb)
#pragma unroll
        for (int rr = 0; rr < 4; ++rr) {
          int prow = lg * 4 + rr;
          int pcol = jb * 16 + l15;
          *(u16*)(pw + prow * 128 + ((pcol * 2) ^ ((prow & 7) << 4))) = f2bf(sc[jb][rr]);
        }
    }

    // O += P V
    {
      const char* pr = (const char*)(Pl + wave * 1024);
      int pswz = (l15 & 7) << 4;
      bf16x8 pa0 = *(const bf16x8*)(pr + l15 * 128 + (((lg * 8) * 2) ^ pswz));
      bf16x8 pa1 = *(const bf16x8*)(pr + l15 * 128 + (((32 + lg * 8) * 2) ^ pswz));
#pragma unroll
      for (int db = 0; db < 8; ++db) {
        int d = db * 16 + l15;
        const char* vb = (const char*)Vl + d * 128;
        int vswz = (d & 7) << 4;
        bf16x8 b0 = *(const bf16x8*)(vb + (((lg * 8) * 2) ^ vswz));
        bf16x8 b1 = *(const bf16x8*)(vb + (((32 + lg * 8) * 2) ^ vswz));
        o[db] = __builtin_amdgcn_mfma_f32_16x16x32_bf16(pa0, b0, o[db], 0, 0, 0);
        o[db] = __builtin_amdgcn_mfma_f32_16x16x32_bf16(pa1, b1, o[db], 0, 0, 0);
      }
    }
    __syncthreads();   // all K/V reads of this step done

    if (t < t1) {
#pragma unroll
      for (int i = 0; i < 4; ++i) {
        *(u16x8*)((char*)Kl + krow[i] * 256 + ((kcol * 2) ^ ((krow[i] & 7) << 4))) = kr[i];
        *(u16x8*)((char*)Vl + vrow[i] * 128 + ((vcol * 2) ^ ((vrow[i] & 7) << 4))) = vr[i];
      }
      __syncthreads();
    }
  }

  if (qt >= 16) {
    // write fp32 partial (O pre-division, m, l)
    const int slot = (h * 16 + (qt - 16)) * 2 + cpart;
    float* Op = Opart + (size_t)slot * 64 * 128;
#pragma unroll
    for (int db = 0; db < 8; ++db)
#pragma unroll
      for (int rr = 0; rr < 4; ++rr) {
        int row = wave * 16 + lg * 4 + rr;
        Op[row * 128 + db * 16 + l15] = o[db][rr];
      }
    if (l15 == 0) {
#pragma unroll
      for (int rr = 0; rr < 4; ++rr) {
        int row = wave * 16 + lg * 4 + rr;
        Mpart[slot * 64 + row] = mrow[rr];
        Lpart[slot * 64 + row] = lrow[rr];
      }
    }
  } else {
    // single-chunk: finalize directly
#pragma unroll
    for (int db = 0; db < 8; ++db) {
      int col = h * 128 + db * 16 + l15;
#pragma unroll
      for (int rr = 0; rr < 4; ++rr) {
        int row = q0 + wave * 16 + lg * 4 + rr;
        aout[(size_t)row * HID + col] = f2bf(o[db][rr] / lrow[rr]);
      }
    }
  }
}

// ---------------- combine the two partials per (h, qt>=16) -> aout ----------------
__global__ void attn_reduce_kernel(const float* __restrict__ Opart,
                                   const float* __restrict__ Mpart,
                                   const float* __restrict__ Lpart,
                                   u16* __restrict__ aout) {
  const int b = blockIdx.x;            // 512 = 32 heads x 16 qtiles
  const int h = b >> 4, qi = b & 15;
  const int qt = 16 + qi;
  const int s0 = (h * 16 + qi) * 2, s1 = s0 + 1;
  const int tid = threadIdx.x;
  const int row = tid >> 2;            // 0..63
  const int colb = (tid & 3) * 32;     // 0,32,64,96

  float m0 = Mpart[s0 * 64 + row], m1 = Mpart[s1 * 64 + row];
  float mm = fmaxf(m0, m1);
  float w0 = __expf(m0 - mm), w1 = __expf(m1 - mm);
  float inv = 1.0f / (w0 * Lpart[s0 * 64 + row] + w1 * Lpart[s1 * 64 + row]);
  w0 *= inv; w1 *= inv;

  const float* O0 = Opart + ((size_t)s0 * 64 + row) * 128 + colb;
  const float* O1 = Opart + ((size_t)s1 * 64 + row) * 128 + colb;
  u16* out = aout + (size_t)(qt * 64 + row) * HID + h * 128 + colb;
#pragma unroll
  for (int j = 0; j < 8; ++j) {
    f32x4 a = *(const f32x4*)(O0 + j * 4);
    f32x4 bb = *(const f32x4*)(O1 + j * 4);
    u16x4 pk;
#pragma unroll
    for (int e = 0; e < 4; ++e) pk[e] = f2bf(w0 * a[e] + w1 * bb[e]);
    *(u16x4*)(out + j * 4) = pk;
  }
}

// ---------------- host launch ----------------
extern "C" void kernel_launch(void* const* d_in, const int* in_sizes, int n_in,
                              void* d_out, int out_size, void* d_ws, size_t ws_size,
                              hipStream_t stream) {
  (void)in_sizes; (void)n_in; (void)out_size; (void)ws_size;
  const float* hs  = (const float*)d_in[0];
  const float* q_w = (const float*)d_in[1];
  const float* q_b = (const float*)d_in[2];
  const float* k_w = (const float*)d_in[3];
  const float* k_b = (const float*)d_in[4];
  const float* v_w = (const float*)d_in[5];
  const float* v_b = (const float*)d_in[6];
  const float* o_w = (const float*)d_in[7];
  const int*   pos = (const int*)d_in[8];

  char* ws = (char*)d_ws;
  u16*   xbf   = (u16*)(ws);                          // [2048][4096]   16.78 MB (dead after QKV gemm)
  u16*   wqkv  = (u16*)(ws + 16777216);               // [5120][4096]   41.94 MB (dead after QKV gemm)
  u16*   owbf  = (u16*)(ws + 58720256);               // [4096][4096]   33.55 MB
  float* bias  = (float*)(ws + 92274688);             // [5120]
  u16*   qkv   = (u16*)(ws + 92295168);               // [2048][5120]   20.97 MB
  u16*   vt    = (u16*)(ws + 113266688);               // [512][2048]     2.10 MB
  u16*   aout  = (u16*)(ws + 115363840);               // [2048][4096]   16.78 MB
  // attention partials overlay the dead xbf/wqkv region:
  float* Opart = (float*)(ws);                        // [1024][64][128] 33.55 MB
  float* Mpart = (float*)(ws + 33554432);             // [1024][64]       0.26 MB
  float* Lpart = (float*)(ws + 33816576);             // [1024][64]       0.26 MB

  cvt_kernel<<<1024, 256, 0, stream>>>(hs,  xbf,                   (2048 * 4096) / 4);
  cvt_kernel<<<1024, 256, 0, stream>>>(q_w, wqkv,                  (4096 * 4096) / 4);
  cvt_kernel<<<512,  256, 0, stream>>>(k_w, wqkv + 4096 * 4096,    (512 * 4096) / 4);
  cvt_kernel<<<512,  256, 0, stream>>>(v_w, wqkv + 4608 * 4096,    (512 * 4096) / 4);
  cvt_kernel<<<1024, 256, 0, stream>>>(o_w, owbf,                  (4096 * 4096) / 4);
  biascat_kernel<<<20, 256, 0, stream>>>(q_b, k_b, v_b, bias);

  gemm_bt_kernel<1, 1><<<dim3(QKV_N / 128, S_TOK / 128), 256, 0, stream>>>(
      xbf, wqkv, qkv, bias, S_TOK, QKV_N, HID);

  rope_kernel<<<(S_TOK * 36) / 4, 256, 0, stream>>>(qkv, pos);
  vtrans_kernel<<<dim3(16, 64), 256, 0, stream>>>(qkv, vt);

  attn_kernel<<<1536, 256, 0, stream>>>(qkv, vt, aout, Opart, Mpart, Lpart);
  attn_reduce_kernel<<<512, 256, 0, stream>>>(Opart, Mpart, Lpart, aout);

  gemm_bt_kernel<0, 0><<<dim3(HID / 128, S_TOK / 128), 256, 0, stream>>>(
      aout, owbf, d_out, nullptr, S_TOK, HID, HID);
}

// Round 4
// 422.885 us; speedup vs baseline: 1.4257x; 1.4257x over previous
//
#include <hip/hip_runtime.h>
#include <stdint.h>

// Qwen2 attention layer: B=1, S=2048, H=4096, NH=32, NKV=4, HD=128, causal GQA + RoPE.
// Pipeline: cvt(fp32->bf16) -> QKV gemm_bt (bf16 MFMA) -> RoPE(+q scale) -> V transpose
//           -> flash attention (KV-split, DMA dbuf staging, fp32 partials) -> reduce -> O gemm_bt.

using bf16x8 = __attribute__((ext_vector_type(8))) short;          // MFMA A/B frag (8 bf16, 4 VGPR)
using f32x4  = __attribute__((ext_vector_type(4))) float;          // MFMA C/D frag
using u16    = unsigned short;
using u16x4  = __attribute__((ext_vector_type(4))) unsigned short; // 8B store
using u16x8  = __attribute__((ext_vector_type(8))) unsigned short; // 16B copy type

#define S_TOK   2048
#define HID     4096
#define QKV_N   5120   // 4096 q + 512 k + 512 v
#define K_OFF   4096
#define V_OFF   4608
#define NHEAD   32
#define NKVH    4

__device__ __forceinline__ float bf2f(u16 u) {
  unsigned v = ((unsigned)u) << 16;
  return __builtin_bit_cast(float, v);
}
__device__ __forceinline__ u16 f2bf(float f) {   // round-to-nearest-even
  unsigned u = __builtin_bit_cast(unsigned, f);
  u += 0x7fffu + ((u >> 16) & 1u);
  return (u16)(u >> 16);
}

// ---------------- fp32 -> bf16 convert (vectorized, grid-stride) ----------------
__global__ void cvt_kernel(const float* __restrict__ src, u16* __restrict__ dst, int n4) {
  int stride = gridDim.x * blockDim.x;
  for (int i = blockIdx.x * blockDim.x + threadIdx.x; i < n4; i += stride) {
    f32x4 v = ((const f32x4*)src)[i];
    union { u16 a[4]; unsigned long long ll; } o;
    o.a[0] = f2bf(v[0]); o.a[1] = f2bf(v[1]); o.a[2] = f2bf(v[2]); o.a[3] = f2bf(v[3]);
    ((unsigned long long*)dst)[i] = o.ll;
  }
}

// ---------------- bias concat (q_b | k_b | v_b) -> fp32[5120] ----------------
__global__ void biascat_kernel(const float* __restrict__ qb, const float* __restrict__ kb,
                               const float* __restrict__ vb, float* __restrict__ out) {
  int i = blockIdx.x * 256 + threadIdx.x;
  if (i >= QKV_N) return;
  float v;
  if (i < K_OFF) v = qb[i];
  else if (i < V_OFF) v = kb[i - K_OFF];
  else v = vb[i - V_OFF];
  out[i] = v;
}

// ---------------- async global->LDS (16B per lane, dest = wave base + lane*16) ----------------
__device__ __forceinline__ void gload_lds16(const void* g, void* l) {
  __builtin_amdgcn_global_load_lds(
      (const __attribute__((address_space(1))) void*)g,
      (__attribute__((address_space(3))) void*)l, 16, 0, 0);
}

// ---------------- GEMM: C[M,N] = A[M,K] @ B[N,K]^T (+bias), bf16 in, fp32 acc ----------------
// m97 structure: 128x128 tile, BK=64, 4 waves (2x2 of 64x64), 16x16x32 bf16 MFMA,
// global_load_lds width 16, single-buffered LDS, 2 barriers per K-step.
// + bijective XCD swizzle (T1).
template <int BF16OUT, int BIAS>
__global__ __launch_bounds__(256, 2)
void gemm_bt_kernel(const u16* __restrict__ A, const u16* __restrict__ Bm,
                    void* __restrict__ C, const float* __restrict__ bias,
                    int M, int N, int K) {
  __shared__ __align__(16) u16 lA[128 * 64];
  __shared__ __align__(16) u16 lB[128 * 64];
  const int tid  = threadIdx.x;
  const int wave = tid >> 6, lane = tid & 63;
  const int lg = lane >> 4, l15 = lane & 15;

  // XCD swizzle (grids here have nwg % 8 == 0)
  const int nwg  = gridDim.x * gridDim.y;
  const int orig = blockIdx.y * gridDim.x + blockIdx.x;
  const int cpx  = nwg >> 3;
  const int swz  = (orig & 7) * cpx + (orig >> 3);
  const int bx   = swz % gridDim.x, by = swz / gridDim.x;

  const int m0 = by * 128, n0 = bx * 128;
  const int wr = wave >> 1, wc = wave & 1;

  f32x4 acc[4][4] = {};

  for (int k0 = 0; k0 < K; k0 += 64) {
#pragma unroll
    for (int i = 0; i < 4; ++i) {
      int c = wave * 4 + i;          // chunk 0..15, 1KB each (64 lanes x 16B)
      int s = c * 64 + lane;         // slot -> row/col of [128][64] tile
      int row = s >> 3;
      int col = (s & 7) << 3;
      gload_lds16(A  + (size_t)(m0 + row) * K + k0 + col, &lA[c * 512]);
      gload_lds16(Bm + (size_t)(n0 + row) * K + k0 + col, &lB[c * 512]);
    }
    __syncthreads();
#pragma unroll
    for (int kk = 0; kk < 2; ++kk) {
      bf16x8 af[4], bfr[4];
#pragma unroll
      for (int mi = 0; mi < 4; ++mi)
        af[mi] = *(const bf16x8*)&lA[(wr * 64 + mi * 16 + l15) * 64 + kk * 32 + lg * 8];
#pragma unroll
      for (int ni = 0; ni < 4; ++ni)
        bfr[ni] = *(const bf16x8*)&lB[(wc * 64 + ni * 16 + l15) * 64 + kk * 32 + lg * 8];
#pragma unroll
      for (int mi = 0; mi < 4; ++mi)
#pragma unroll
        for (int ni = 0; ni < 4; ++ni)
          acc[mi][ni] = __builtin_amdgcn_mfma_f32_16x16x32_bf16(af[mi], bfr[ni], acc[mi][ni], 0, 0, 0);
    }
    __syncthreads();
  }

  // epilogue: D layout col=lane&15, row=(lane>>4)*4+reg  [m89-verified]
#pragma unroll
  for (int mi = 0; mi < 4; ++mi) {
#pragma unroll
    for (int ni = 0; ni < 4; ++ni) {
      int r0 = m0 + wr * 64 + mi * 16 + lg * 4;
      int cc = n0 + wc * 64 + ni * 16 + l15;
      float bv = BIAS ? bias[cc] : 0.0f;
#pragma unroll
      for (int r = 0; r < 4; ++r) {
        float v = acc[mi][ni][r] + bv;
        if (BF16OUT) ((u16*)C)[(size_t)(r0 + r) * N + cc] = f2bf(v);
        else         ((float*)C)[(size_t)(r0 + r) * N + cc] = v;
      }
    }
  }
}

// ---------------- RoPE in-place on q,k regions of qkv; folds 1/sqrt(HD) into q ----------------
__global__ void rope_kernel(u16* __restrict__ qkv, const int* __restrict__ pos_ids) {
  const int tid  = threadIdx.x;
  const int gid  = blockIdx.x * 4 + (tid >> 6);   // (s, head) pair; 2048*36 total
  const int lane = tid & 63;                       // d in [0,64)
  const int s = gid / 36, hh = gid - s * 36;       // hh: 0..31 q heads, 32..35 k heads
  const float pos = (float)pos_ids[s];
  const float inv = exp2f((float)lane * -0.20762050593f);  // 10000^(-d/64)
  float sn, cs;
  sincosf(pos * inv, &sn, &cs);
  size_t base = (size_t)s * QKV_N + (hh < 32 ? hh * 128 : K_OFF + (hh - 32) * 128);
  float x1 = bf2f(qkv[base + lane]);
  float x2 = bf2f(qkv[base + lane + 64]);
  float o1 = x1 * cs - x2 * sn;
  float o2 = x2 * cs + x1 * sn;
  if (hh < 32) { o1 *= 0.08838834764831845f; o2 *= 0.08838834764831845f; }
  qkv[base + lane]      = f2bf(o1);
  qkv[base + lane + 64] = f2bf(o2);
}

// ---------------- V transpose: qkv v-cols [2048][512] -> vt [512][2048] ----------------
__global__ void vtrans_kernel(const u16* __restrict__ qkv, u16* __restrict__ vt) {
  __shared__ u16 t[32][33];
  const int tx = threadIdx.x & 31, ty = threadIdx.x >> 5;  // 32x8
  const int bc = blockIdx.x;  // 16 col tiles (512/32)
  const int bs = blockIdx.y;  // 64 row tiles (2048/32)
#pragma unroll
  for (int i = 0; i < 4; ++i)
    t[ty + i * 8][tx] = qkv[(size_t)(bs * 32 + ty + i * 8) * QKV_N + V_OFF + bc * 32 + tx];
  __syncthreads();
#pragma unroll
  for (int i = 0; i < 4; ++i)
    vt[(size_t)(bc * 32 + ty + i * 8) * S_TOK + bs * 32 + tx] = t[tx][ty + i * 8];
}

// ---------------- Flash attention: KV-split + DMA dbuf staging ----------------
// Grid: 1536 blocks. XCD-affine mapping (bid&7 = XCD, 2 XCDs per kvh group):
//   kvh = (bid&7)>>1, item = (bid>>3)*2 + (bid&1), h = kvh*8 + item/48, r = item%48.
// Per (h, r):
//   r in [0,16):  qt = 16+r, tiles [0,16)  no diag  -> partial slot cpart=0
//   r in [16,32): qt = 47-r, tiles [16,qt] diag     -> partial slot cpart=1
//   r in [32,48): qt = 47-r, tiles [0,qt]  diag     -> direct aout
// Every WG <=16 KV tiles. Inner loop = round-2 verified body: global_load_lds dbuf
// with pre-swizzled source, one barrier per step. LDS 72KB -> 2 blocks/CU, VGPR ~88.
__global__ __launch_bounds__(256, 2)
void attn_kernel(const u16* __restrict__ qkv, const u16* __restrict__ vt,
                 u16* __restrict__ aout, float* __restrict__ Opart,
                 float* __restrict__ Mpart, float* __restrict__ Lpart) {
  __shared__ __align__(16) u16 Kl[2][64 * 128];   // K tile, rows 256B, chunk-swizzled
  __shared__ __align__(16) u16 Vl[2][128 * 64];   // V^T tile, rows 128B, chunk-swizzled
  __shared__ __align__(16) u16 Pl[4 * 16 * 64];   // per-wave P, XOR-swizzled rows (128B)
  const int tid = threadIdx.x, wave = tid >> 6, lane = tid & 63;
  const int lg = lane >> 4, l15 = lane & 15;

  const int bid  = blockIdx.x;
  const int xcd  = bid & 7;
  const int idx  = bid >> 3;
  const int kvh  = xcd >> 1;
  const int item = idx * 2 + (xcd & 1);
  const int h    = (kvh << 3) + item / 48;
  const int r    = item % 48;

  int qt, t0, t1, cpart;
  bool diag;
  if (r < 16)      { qt = 16 + r; t0 = 0;  t1 = 15; cpart = 0; diag = false; }
  else if (r < 32) { qt = 47 - r; t0 = 16; t1 = qt; cpart = 1; diag = true;  }
  else             { qt = 47 - r; t0 = 0;  t1 = qt; cpart = 0; diag = true;  }
  const int q0 = qt * 64;

  // Q fragments hoisted to registers (A-frag: row = lane&15, k = (lane>>4)*8, +kk*32)
  bf16x8 qf[4];
  {
    const u16* qp = qkv + (size_t)(q0 + wave * 16 + l15) * QKV_N + h * 128 + lg * 8;
#pragma unroll
    for (int kk = 0; kk < 4; ++kk) qf[kk] = *(const bf16x8*)(qp + kk * 32);
  }

  // Per-lane pre-swizzled global source pointers for DMA staging (tile-0 based).
  // K tile: 16 chunks of 1KB; chunk c = rows 4c..4c+3 (256B rows); lane: row=4c+(lane>>4), ch=lane&15.
  // V tile: 16 chunks of 1KB; chunk c = rows 8c..8c+7 (128B rows); lane: row=8c+(lane>>3), ch=lane&7.
  const u16* kp[4];
  const u16* vp[4];
  const int kc0 = wave * 4;
#pragma unroll
  for (int i = 0; i < 4; ++i) {
    int krow = (kc0 + i) * 4 + (lane >> 4);
    int kch  = lane & 15;
    kp[i] = qkv + K_OFF + kvh * 128 + (size_t)krow * QKV_N + ((kch ^ (krow & 7)) * 8);
    int vrow = (kc0 + i) * 8 + (lane >> 3);     // d index 0..127
    int vch  = lane & 7;
    vp[i] = vt + (size_t)(kvh * 128 + vrow) * S_TOK + ((vch ^ (vrow & 7)) * 8);
  }

  f32x4 o[8];
#pragma unroll
  for (int i = 0; i < 8; ++i) o[i] = f32x4{0.f, 0.f, 0.f, 0.f};
  float mrow[4] = {-3e38f, -3e38f, -3e38f, -3e38f};
  float lrow[4] = {0.f, 0.f, 0.f, 0.f};

  // prologue: stage tile t0 into buf (t0&1)
#pragma unroll
  for (int i = 0; i < 4; ++i) {
    gload_lds16(kp[i] + (size_t)t0 * 64 * QKV_N, &Kl[t0 & 1][(kc0 + i) * 512]);
    gload_lds16(vp[i] + t0 * 64,                 &Vl[t0 & 1][(kc0 + i) * 512]);
  }
  __syncthreads();

  for (int t = t0; t <= t1; ++t) {
    const int cur = t & 1;
    // issue DMA for tile t+1 into the other buffer; in flight across this step's compute
    if (t < t1) {
      const size_t koff = (size_t)(t + 1) * 64 * QKV_N;
      const int    voff = (t + 1) * 64;
#pragma unroll
      for (int i = 0; i < 4; ++i) {
        gload_lds16(kp[i] + koff, &Kl[cur ^ 1][(kc0 + i) * 512]);
        gload_lds16(vp[i] + voff, &Vl[cur ^ 1][(kc0 + i) * 512]);
      }
    }
    const int kv0 = t * 64;
    const bool dg = diag && (t == t1);

    // S = Q K^T (per wave: 16 rows x 64 cols = 4 j-frags, K over d=128)
    f32x4 sc[4];
#pragma unroll
    for (int jb = 0; jb < 4; ++jb) {
      f32x4 a = {0.f, 0.f, 0.f, 0.f};
      int j = jb * 16 + l15;
      const char* kb = (const char*)&Kl[cur][0] + j * 256;
      int swzk = (j & 7) << 4;
#pragma unroll
      for (int kk = 0; kk < 4; ++kk) {
        bf16x8 bfr = *(const bf16x8*)(kb + (((kk * 32 + lg * 8) * 2) ^ swzk));
        a = __builtin_amdgcn_mfma_f32_16x16x32_bf16(qf[kk], bfr, a, 0, 0, 0);
      }
      sc[jb] = a;
    }

    // causal mask (diag tile only) + online softmax; rows r_local = lg*4+rr
    float tmax[4] = {-3e38f, -3e38f, -3e38f, -3e38f};
#pragma unroll
    for (int jb = 0; jb < 4; ++jb) {
      int jg = kv0 + jb * 16 + l15;
#pragma unroll
      for (int rr = 0; rr < 4; ++rr) {
        float v = sc[jb][rr];
        if (dg && (jg > q0 + wave * 16 + lg * 4 + rr)) v = -3e38f;
        sc[jb][rr] = v;
        tmax[rr] = fmaxf(tmax[rr], v);
      }
    }
#pragma unroll
    for (int off = 1; off < 16; off <<= 1)
#pragma unroll
      for (int rr = 0; rr < 4; ++rr) tmax[rr] = fmaxf(tmax[rr], __shfl_xor(tmax[rr], off, 64));
    float alpha[4], psum[4];
#pragma unroll
    for (int rr = 0; rr < 4; ++rr) {
      float mn = fmaxf(mrow[rr], tmax[rr]);
      alpha[rr] = __expf(mrow[rr] - mn);
      mrow[rr] = mn;
      psum[rr] = 0.f;
    }
#pragma unroll
    for (int jb = 0; jb < 4; ++jb)
#pragma unroll
      for (int rr = 0; rr < 4; ++rr) {
        float p = __expf(sc[jb][rr] - mrow[rr]);
        sc[jb][rr] = p;
        psum[rr] += p;
      }
#pragma unroll
    for (int off = 1; off < 16; off <<= 1)
#pragma unroll
      for (int rr = 0; rr < 4; ++rr) psum[rr] += __shfl_xor(psum[rr], off, 64);
#pragma unroll
    for (int rr = 0; rr < 4; ++rr) lrow[rr] = lrow[rr] * alpha[rr] + psum[rr];
#pragma unroll
    for (int db = 0; db < 8; ++db)
#pragma unroll
      for (int rr = 0; rr < 4; ++rr) o[db][rr] *= alpha[rr];

    // write P (bf16) to per-wave LDS region (wave-private; no cross-wave barrier needed)
    {
      char* pw = (char*)(Pl + wave * 1024);
#pragma unroll
      for (int jb = 0; jb < 4; ++jb)
#pragma unroll
        for (int rr = 0; rr < 4; ++rr) {
          int prow = lg * 4 + rr;
          int pcol = jb * 16 + l15;
          *(u16*)(pw + prow * 128 + ((pcol * 2) ^ ((prow & 7) << 4))) = f2bf(sc[jb][rr]);
        }
    }

    // O += P V  (A-frag from Pl, B-frag from Vl; K = 64 -> 2 MFMAs per d-frag)
    {
      const char* pr = (const char*)(Pl + wave * 1024);
      int pswz = (l15 & 7) << 4;
      bf16x8 pa0 = *(const bf16x8*)(pr + l15 * 128 + (((lg * 8) * 2) ^ pswz));
      bf16x8 pa1 = *(const bf16x8*)(pr + l15 * 128 + (((32 + lg * 8) * 2) ^ pswz));
#pragma unroll
      for (int db = 0; db < 8; ++db) {
        int d = db * 16 + l15;
        const char* vb = (const char*)&Vl[cur][0] + d * 128;
        int vswz = (d & 7) << 4;
        bf16x8 b0 = *(const bf16x8*)(vb + (((lg * 8) * 2) ^ vswz));
        bf16x8 b1 = *(const bf16x8*)(vb + (((32 + lg * 8) * 2) ^ vswz));
        o[db] = __builtin_amdgcn_mfma_f32_16x16x32_bf16(pa0, b0, o[db], 0, 0, 0);
        o[db] = __builtin_amdgcn_mfma_f32_16x16x32_bf16(pa1, b1, o[db], 0, 0, 0);
      }
    }
    __syncthreads();   // single per-step drain: t+1 DMA complete + all buf reads done
  }

  if (qt >= 16) {
    // write fp32 partial (O pre-division, m, l)
    const int slot = (h * 16 + (qt - 16)) * 2 + cpart;
    float* Op = Opart + (size_t)slot * 64 * 128;
#pragma unroll
    for (int db = 0; db < 8; ++db)
#pragma unroll
      for (int rr = 0; rr < 4; ++rr) {
        int row = wave * 16 + lg * 4 + rr;
        Op[row * 128 + db * 16 + l15] = o[db][rr];
      }
    if (l15 == 0) {
#pragma unroll
      for (int rr = 0; rr < 4; ++rr) {
        int row = wave * 16 + lg * 4 + rr;
        Mpart[slot * 64 + row] = mrow[rr];
        Lpart[slot * 64 + row] = lrow[rr];
      }
    }
  } else {
    // single-chunk: finalize directly
#pragma unroll
    for (int db = 0; db < 8; ++db) {
      int col = h * 128 + db * 16 + l15;
#pragma unroll
      for (int rr = 0; rr < 4; ++rr) {
        int row = q0 + wave * 16 + lg * 4 + rr;
        aout[(size_t)row * HID + col] = f2bf(o[db][rr] / lrow[rr]);
      }
    }
  }
}

// ---------------- combine the two partials per (h, qt>=16) -> aout ----------------
__global__ void attn_reduce_kernel(const float* __restrict__ Opart,
                                   const float* __restrict__ Mpart,
                                   const float* __restrict__ Lpart,
                                   u16* __restrict__ aout) {
  const int b = blockIdx.x;            // 512 = 32 heads x 16 qtiles
  const int h = b >> 4, qi = b & 15;
  const int qt = 16 + qi;
  const int s0 = (h * 16 + qi) * 2, s1 = s0 + 1;
  const int tid = threadIdx.x;
  const int row = tid >> 2;            // 0..63
  const int colb = (tid & 3) * 32;     // 0,32,64,96

  float m0 = Mpart[s0 * 64 + row], m1 = Mpart[s1 * 64 + row];
  float mm = fmaxf(m0, m1);
  float w0 = __expf(m0 - mm), w1 = __expf(m1 - mm);
  float inv = 1.0f / (w0 * Lpart[s0 * 64 + row] + w1 * Lpart[s1 * 64 + row]);
  w0 *= inv; w1 *= inv;

  const float* O0 = Opart + ((size_t)s0 * 64 + row) * 128 + colb;
  const float* O1 = Opart + ((size_t)s1 * 64 + row) * 128 + colb;
  u16* out = aout + (size_t)(qt * 64 + row) * HID + h * 128 + colb;
#pragma unroll
  for (int j = 0; j < 8; ++j) {
    f32x4 a = *(const f32x4*)(O0 + j * 4);
    f32x4 bb = *(const f32x4*)(O1 + j * 4);
    u16x4 pk;
#pragma unroll
    for (int e = 0; e < 4; ++e) pk[e] = f2bf(w0 * a[e] + w1 * bb[e]);
    *(u16x4*)(out + j * 4) = pk;
  }
}

// ---------------- host launch ----------------
extern "C" void kernel_launch(void* const* d_in, const int* in_sizes, int n_in,
                              void* d_out, int out_size, void* d_ws, size_t ws_size,
                              hipStream_t stream) {
  (void)in_sizes; (void)n_in; (void)out_size; (void)ws_size;
  const float* hs  = (const float*)d_in[0];
  const float* q_w = (const float*)d_in[1];
  const float* q_b = (const float*)d_in[2];
  const float* k_w = (const float*)d_in[3];
  const float* k_b = (const float*)d_in[4];
  const float* v_w = (const float*)d_in[5];
  const float* v_b = (const float*)d_in[6];
  const float* o_w = (const float*)d_in[7];
  const int*   pos = (const int*)d_in[8];

  char* ws = (char*)d_ws;
  u16*   xbf   = (u16*)(ws);                          // [2048][4096]   16.78 MB (dead after QKV gemm)
  u16*   wqkv  = (u16*)(ws + 16777216);               // [5120][4096]   41.94 MB (dead after QKV gemm)
  u16*   owbf  = (u16*)(ws + 58720256);               // [4096][4096]   33.55 MB
  float* bias  = (float*)(ws + 92274688);             // [5120]
  u16*   qkv   = (u16*)(ws + 92295168);               // [2048][5120]   20.97 MB
  u16*   vt    = (u16*)(ws + 113266688);              // [512][2048]     2.10 MB
  u16*   aout  = (u16*)(ws + 115363840);              // [2048][4096]   16.78 MB
  // attention partials overlay the dead xbf/wqkv region:
  float* Opart = (float*)(ws);                        // [1024][64][128] 33.55 MB
  float* Mpart = (float*)(ws + 33554432);             // [1024][64]       0.26 MB
  float* Lpart = (float*)(ws + 33816576);             // [1024][64]       0.26 MB

  cvt_kernel<<<1024, 256, 0, stream>>>(hs,  xbf,                   (2048 * 4096) / 4);
  cvt_kernel<<<1024, 256, 0, stream>>>(q_w, wqkv,                  (4096 * 4096) / 4);
  cvt_kernel<<<512,  256, 0, stream>>>(k_w, wqkv + 4096 * 4096,    (512 * 4096) / 4);
  cvt_kernel<<<512,  256, 0, stream>>>(v_w, wqkv + 4608 * 4096,    (512 * 4096) / 4);
  cvt_kernel<<<1024, 256, 0, stream>>>(o_w, owbf,                  (4096 * 4096) / 4);
  biascat_kernel<<<20, 256, 0, stream>>>(q_b, k_b, v_b, bias);

  gemm_bt_kernel<1, 1><<<dim3(QKV_N / 128, S_TOK / 128), 256, 0, stream>>>(
      xbf, wqkv, qkv, bias, S_TOK, QKV_N, HID);

  rope_kernel<<<(S_TOK * 36) / 4, 256, 0, stream>>>(qkv, pos);
  vtrans_kernel<<<dim3(16, 64), 256, 0, stream>>>(qkv, vt);

  attn_kernel<<<1536, 256, 0, stream>>>(qkv, vt, aout, Opart, Mpart, Lpart);
  attn_reduce_kernel<<<512, 256, 0, stream>>>(Opart, Mpart, Lpart, aout);

  gemm_bt_kernel<0, 0><<<dim3(HID / 128, S_TOK / 128), 256, 0, stream>>>(
      aout, owbf, d_out, nullptr, S_TOK, HID, HID);
}